// Round 11
// baseline (5501.210 us; speedup 1.0000x reference)
//
#include <hip/hip_runtime.h>
#include <cstdint>
#include <cstddef>

typedef unsigned long long u64;
typedef unsigned int u32;

#define NROWS 8192
#define DIN   1024
#define DOUT  4096
#define GAMMA 0.01618f
#define NC    640                 // exact candidate depth: 620 max suppressed + 10 + margin
#define RQ    2048                // u64 stride between candidate rows (16 KB = one H row)
#define BATCH 8                   // speculative rows per batch (r1-validated structure)
#define NCHUNK 128                // 8192 / 64 rows per ready-chunk
#define TQ_SPAN 8447u             // 8192 topk tickets + 255 overshoots per launch

typedef _Float16 f16x8 __attribute__((ext_vector_type(8)));
typedef float    f32x4 __attribute__((ext_vector_type(4)));

// ---- persistent device state: MONOTONIC across launches (no reset needed) ----
__device__ u32 g_blk = 0;                 // +256 per launch; epoch k = val>>8
__device__ u32 g_tq  = 0;                 // topk ticket counter: +TQ_SPAN per launch
__device__ u32 g_chunkDone[NCHUNK] = {};  // per-64-row chunk: +64 per launch

#define SCOPE __HIP_MEMORY_SCOPE_AGENT

// monotone order-preserving fp32 -> u32 (ascending); s>0 <=> key > 0x80000000
__device__ __forceinline__ u32 mono_key(float f) {
    u32 u = __float_as_uint(f);
    return (u & 0x80000000u) ? ~u : (u | 0x80000000u);
}
__device__ __forceinline__ u32 unmono_key(u32 u) {
    return (u & 0x80000000u) ? (u ^ 0x80000000u) : ~u;
}

__device__ __forceinline__ u64 wave_max64(u64 x) {
#pragma unroll
    for (int off = 32; off >= 1; off >>= 1) {
        u32 lo = (u32)x, hi = (u32)(x >> 32);
        u32 olo = __shfl_xor(lo, off, 64);
        u32 ohi = __shfl_xor(hi, off, 64);
        u64 o = ((u64)ohi << 32) | olo;
        if (o > x) x = o;
    }
    return x;
}
__device__ __forceinline__ u64 shfl_u64(u64 x, int src) {
    u32 lo = __shfl((u32)x, src, 64);
    u32 hi = __shfl((u32)(x >> 32), src, 64);
    return ((u64)hi << 32) | lo;
}

__device__ __forceinline__ void gl16(const void* g, void* l) {
    __builtin_amdgcn_global_load_lds(
        (const __attribute__((address_space(1))) unsigned int*)g,
        (__attribute__((address_space(3))) unsigned int*)l, 16, 0, 0);
}

// ---------------------------------------------------------------------------
// K0 (exact r1, validated): split f32 -> f16 hi/lo pair, K-PERMUTED layout.
// ---------------------------------------------------------------------------
__global__ __launch_bounds__(256)
void split_kernel(const float* __restrict__ X, const float* __restrict__ W,
                  _Float16* __restrict__ X1, _Float16* __restrict__ X2,
                  _Float16* __restrict__ W1, _Float16* __restrict__ W2) {
    int t = blockIdx.x * 256 + threadIdx.x;
    const int NXG = (NROWS * DIN) / 8;       // 1048576 granules of 8
    const int NWG = (DOUT * DIN) / 8;        // 524288
    if (t >= NXG + NWG) return;
    const float* src; _Float16* d1; _Float16* d2; int row, g8;
    if (t < NXG) { src = X; d1 = X1; d2 = X2; row = t >> 7; g8 = t & 127; }
    else { int u = t - NXG; src = W; d1 = W1; d2 = W2; row = u >> 7; g8 = u & 127; }
    const int kb = g8 >> 2, gp = g8 & 3;
    const int g  = gp ^ ((row >> 1) & 3);
    const int kbase = kb * 32 + g * 4;
    const float* p = src + (size_t)row * DIN + kbase;
    float4 lo = *(const float4*)p;           // k = kbase .. kbase+3   (e=0..3)
    float4 hi = *(const float4*)(p + 16);    // k = kbase+16 .. +19    (e=4..7)
    float xs[8] = {lo.x, lo.y, lo.z, lo.w, hi.x, hi.y, hi.z, hi.w};
    f16x8 v1, v2;
#pragma unroll
    for (int e = 0; e < 8; ++e) {
        float x  = xs[e];
        float x1 = (float)(_Float16)x;
        if (fabsf(x1) < 6.103515625e-05f) x1 = 0.0f;   // f16 min normal
        v1[e] = (_Float16)x1;
        v2[e] = (_Float16)((x - x1) * 2048.0f);
    }
    size_t o = (size_t)row * DIN + (size_t)g8 * 8;
    *(f16x8*)(d1 + o) = v1;
    *(f16x8*)(d2 + o) = v2;
}

// ---------------------------------------------------------------------------
// K1 v4 (r11): 128x128 tile, 8 waves (2M x 4N), 2-phase double-buffered
// global_load_lds staging (64 KB LDS, 2 blocks/CU). BIT-EXACT vs r9: each
// wave computes the same 4x2 fragment set with identical k-order, identical
// 3-MFMA sequence, identical f64 flush cadence and epilogue math — only the
// block->output mapping and LDS geometry change. Staging drops 3->2 B per
// output-K (33% less traffic), 4 gl16/thread (was 6).
// ---------------------------------------------------------------------------
__global__ __launch_bounds__(512, 2)
void gemm_f16x2_mfma(const _Float16* __restrict__ X1, const _Float16* __restrict__ X2,
                     const _Float16* __restrict__ W1, const _Float16* __restrict__ W2,
                     const float* __restrict__ bias, float* __restrict__ H) {
    __shared__ _Float16 SM[2][16384];   // 64 KB: per buf A1@0 A2@4096 B1@8192 B2@12288
    const int tid  = threadIdx.x;
    const int lane = tid & 63, w = tid >> 6;
    const int wm = w >> 2, wn = w & 3;
    const int m0 = blockIdx.y * 128, n0 = blockIdx.x * 128;

    // --- staging plan: 2048 granules x 16B per K-step, 4 per thread ---
    const char* gp4[4];
    unsigned loff[4];
#pragma unroll
    for (int q = 0; q < 4; ++q) {
        int G = tid + q * 512;
        const char* base; int rowg, c;
        if (G < 1024) {                       // A region: 2 splits x 128 rows x 4
            int s = G >> 9, rem = G & 511; rowg = m0 + (rem >> 2); c = rem & 3;
            base = (const char*)(s ? X2 : X1);
        } else {                              // B region: 2 splits x 128 rows x 4
            int Gb = G - 1024;
            int s = Gb >> 9, rem = Gb & 511; rowg = n0 + (rem >> 2); c = rem & 3;
            base = (const char*)(s ? W2 : W1);
        }
        gp4[q]  = base + (size_t)rowg * (DIN * 2) + (size_t)c * 16;
        loff[q] = (unsigned)((w * 64 + q * 512) * 16);   // wave-uniform LDS base
    }

    f32x4 accHH[4][2], accM[4][2];
    double hd[4][2][4];
    const f32x4 z4 = {0.f, 0.f, 0.f, 0.f};
#pragma unroll
    for (int i = 0; i < 4; ++i)
#pragma unroll
        for (int j = 0; j < 2; ++j) {
            accHH[i][j] = z4; accM[i][j] = z4;
#pragma unroll
            for (int r = 0; r < 4; ++r) hd[i][j][r] = 0.0;
        }

    const int fr  = lane & 15;
    const int gsw = (lane >> 4) ^ ((lane >> 1) & 3);   // swizzled k-group slot
    const int aoff = fr * 32 + gsw * 8;
    const int boff = 8192 + (wn * 32 + fr) * 32 + gsw * 8;

    // prologue: stage K-step 0 into buf 0
#pragma unroll
    for (int q = 0; q < 4; ++q)
        gl16(gp4[q], (char*)SM[0] + loff[q]);
    __syncthreads();                          // buf0 ready

    for (int ks = 0; ks < 32; ++ks) {
        const int cur = ks & 1;
        // issue next tile's stage FIRST (overlaps with ds_read+MFMA below)
        if (ks < 31) {
#pragma unroll
            for (int q = 0; q < 4; ++q)
                gl16(gp4[q] + (size_t)(ks + 1) * 64, (char*)SM[cur ^ 1] + loff[q]);
        }

        const _Float16* SMf = SM[cur];
        f16x8 a1[4], a2[4], b1[2], b2[2];
#pragma unroll
        for (int i = 0; i < 4; ++i) {
            const _Float16* pa = SMf + (wm * 64 + i * 16) * 32 + aoff;
            a1[i] = *(const f16x8*)pa;
            a2[i] = *(const f16x8*)(pa + 4096);          // split-1, +8 KB
        }
#pragma unroll
        for (int j = 0; j < 2; ++j) {
            const _Float16* pb = SMf + boff + j * 16 * 32;
            b1[j] = *(const f16x8*)pb;
            b2[j] = *(const f16x8*)(pb + 4096);          // split-1, +8 KB
        }
#pragma unroll
        for (int i = 0; i < 4; ++i)
#pragma unroll
            for (int j = 0; j < 2; ++j) {
                accHH[i][j] = __builtin_amdgcn_mfma_f32_16x16x32_f16(a1[i], b1[j], accHH[i][j], 0, 0, 0);
                accM[i][j]  = __builtin_amdgcn_mfma_f32_16x16x32_f16(a1[i], b2[j], accM[i][j],  0, 0, 0);
                accM[i][j]  = __builtin_amdgcn_mfma_f32_16x16x32_f16(a2[i], b1[j], accM[i][j],  0, 0, 0);
            }
        if (ks & 1) {                         // flush dominant term to f64
#pragma unroll
            for (int i = 0; i < 4; ++i)
#pragma unroll
                for (int j = 0; j < 2; ++j) {
#pragma unroll
                    for (int r = 0; r < 4; ++r) hd[i][j][r] += (double)accHH[i][j][r];
                    accHH[i][j] = z4;
                }
        }
        __syncthreads();                      // one barrier per K-step
    }

    const int fq = lane >> 4;
#pragma unroll
    for (int i = 0; i < 4; ++i)
#pragma unroll
        for (int j = 0; j < 2; ++j) {
            const int col = n0 + wn * 32 + j * 16 + fr;
            const double bb = (double)bias[col];
#pragma unroll
            for (int r = 0; r < 4; ++r) {
                const int row = m0 + wm * 64 + i * 16 + fq * 4 + r;
                double v = hd[i][j][r] + (double)accM[i][j][r] * (1.0 / 2048.0) + bb;
                float h = (float)v;
                h = (h >= 0.0f) ? h : 0.01f * h;
                H[(size_t)row * DOUT + col] = h;
            }
        }
}

// ---------------------------------------------------------------------------
// top-640 row (worker role; r3/r4/r7-validated 512-thread port of K2) +
// out-row zero + chunk release-increment. EXACT r7/r9 version.
// ---------------------------------------------------------------------------
__device__ void topk_row(u32 r, float* __restrict__ H, float* __restrict__ out,
                         char* dsm, int tid, u32 k) {
    u32* skey  = (u32*)dsm;                   // 16 KB
    int* hist  = (int*)(dsm + 16384);         // 16 KB
    u64* scand = (u64*)(dsm + 32768);         // 8 KB
    int* seg   = (int*)(dsm + 40960);         // 1 KB
    int* s_b   = (int*)(dsm + 41984);
    int* s_cnt = s_b + 1;

    float* hrow = H + (size_t)r * DOUT;
#pragma unroll
    for (int c = 0; c < 2; c++) {
        int j = c * 2048 + tid * 4;
        float4 v = *(const float4*)(hrow + j);
        skey[j + 0] = mono_key(v.x); skey[j + 1] = mono_key(v.y);
        skey[j + 2] = mono_key(v.z); skey[j + 3] = mono_key(v.w);
    }
#pragma unroll
    for (int c = 0; c < 8; c++) hist[c * 512 + tid] = 0;
    if (tid == 0) *s_cnt = 0;
    __syncthreads();
#pragma unroll
    for (int c = 0; c < 2; c++) {
        int j = c * 2048 + tid * 4;
        atomicAdd(&hist[skey[j + 0] >> 20], 1);
        atomicAdd(&hist[skey[j + 1] >> 20], 1);
        atomicAdd(&hist[skey[j + 2] >> 20], 1);
        atomicAdd(&hist[skey[j + 3] >> 20], 1);
    }
    __syncthreads();
    if (tid < 256) {
        int ssum = 0;
#pragma unroll
        for (int i = 0; i < 16; i++) ssum += hist[tid * 16 + i];
        seg[tid] = ssum;
    }
    __syncthreads();
    if (tid == 0) {
        int cum = 0, ts;
        for (ts = 255; ts >= 0; ts--) {
            if (cum + seg[ts] >= NC) break;
            cum += seg[ts];
        }
        int b = 0;
        if (ts >= 0) {
            int bin;
            for (bin = ts * 16 + 15; bin >= ts * 16; bin--) {
                cum += hist[bin];
                if (cum >= NC) break;
            }
            b = (bin < ts * 16) ? ts * 16 : bin;
        }
        *s_b = b;
    }
    __syncthreads();
    const int b = *s_b;
#pragma unroll
    for (int c = 0; c < 2; c++) {
        int jb = c * 2048 + tid * 4;
#pragma unroll
        for (int q = 0; q < 4; q++) {
            int j = jb + q;
            u32 kk = skey[j];
            if ((int)(kk >> 20) >= b) {
                int pos = atomicAdd(s_cnt, 1);
                if (pos < 1024)
                    scand[pos] = ((u64)kk << 32) | (u32)(0xFFFFu - (u32)j);
            }
        }
    }
    __syncthreads();
    int C = *s_cnt; if (C > 1024) C = 1024;
    for (int j = C + tid; j < 1024; j += 512) scand[j] = 0;   // pad sorts last
    for (int size = 2; size <= 1024; size <<= 1)
        for (int stride = size >> 1; stride > 0; stride >>= 1) {
            __syncthreads();
            {
                int i = tid;
                int pos = 2 * i - (i & (stride - 1));
                u64 a = scand[pos], bb = scand[pos + stride];
                bool up = (pos & size) == 0;
                if ((a < bb) == up) { scand[pos] = bb; scand[pos + stride] = a; }
            }
        }
    __syncthreads();
    u64* cand = (u64*)hrow;
    for (int j = tid; j < NC; j += 512) cand[j] = scand[j];
    // zero this row of out (replaces host memset; must precede chunk flag)
    {
        float4 z = {0.f, 0.f, 0.f, 0.f};
        float4* po = (float4*)(out + (size_t)r * DOUT);
        po[tid] = z; po[tid + 512] = z;
    }
    __syncthreads();
    if (tid == 0)
        __hip_atomic_fetch_add(&g_chunkDone[r >> 6], 1u, __ATOMIC_RELEASE, SCOPE);
}

// ---------------------------------------------------------------------------
// r8/r9-validated per-row exact top-10 (fast path + beater-merge + fallback).
// REVERTED to the r9 version (r10's bitonic fallback was -40 us).
// ---------------------------------------------------------------------------
__device__ __forceinline__ void row_top10(
    int m, u64 c, u64 k64, const u64* __restrict__ crow,
    const int* last_sel, float tbl_r, int lane, u64 lmask_lt,
    bool& sel, u32& mid)
{
    const int id = 0xFFFF - (int)(c & 0xFFFFu);
    int t = m - last_sel[id] - 1; if (t > 63) t = 63;
    const bool unsup = (t >= 62);            // tbl saturates to exactly 1 at 62
    const u64 mu = __ballot(unsup);
    const float phi = __shfl(tbl_r, t);
    const float v = __uint_as_float(unmono_key((u32)(c >> 32)));
    const float s = v * phi;
    const u64 skey = ((u64)mono_key(s) << 32) | (c & 0xFFFFu);
    const int nu = __popcll(mu);
    const int prefix = __popcll(mu & lmask_lt);

    bool resolved = false, win = false;
    if (nu >= 10) {
        u64 um = mu;
#pragma unroll
        for (int q = 0; q < 9; q++) um &= um - 1;
        const int lane10 = __ffsll((long long)um) - 1;
        const u64 key10 = shfl_u64(skey, lane10);
        const u64 beat = __ballot(skey > key10) & ~mu;
        u64 theta;
        if (beat == 0ull) {
            win = unsup && (prefix < 10);
            theta = key10;
        } else {
            int myExtra = 0, myrank = 64;
            u64 bm = beat;
            while (bm) {
                const int l = __ffsll((long long)bm) - 1;
                bm &= bm - 1;
                const u64 kb = shfl_u64(skey, l);
                const u64 g = __ballot(skey > kb);
                if (lane == l) myrank = __popcll(g);
                myExtra += (kb > skey) ? 1 : 0;
            }
            const bool isbeat = (beat >> lane) & 1ull;
            const int rank = unsup ? (prefix + myExtra) : (isbeat ? myrank : 64);
            win = rank < 10;
            const u64 r9 = __ballot(rank == 9);
            const int l9 = __ffsll((long long)r9) - 1;
            theta = shfl_u64(skey, l9);
        }
        resolved = ((u32)(theta >> 32) > 0x80000000u) && (theta > k64);
    }

    if (resolved) {
        sel = win; mid = (u32)id;
        return;
    }
    // ---- r6-validated exact fallback over up to 640 candidates ----
    u64 tt[10];
    u64 key = skey, key2 = 0;
#pragma unroll 1
    for (int it = 0; it < 10; it++) {
        if (it > 0) {
            u64 ck = crow[it * 64 + lane];
            u32 hbits = unmono_key((u32)(ck >> 32));
            int id2 = 0xFFFF - (int)(ck & 0xFFFFu);
            int t2 = m - last_sel[id2] - 1; if (t2 > 63) t2 = 63;
            float s2 = __uint_as_float(hbits) * __shfl(tbl_r, t2);
            key = ((u64)mono_key(s2) << 32) | (ck & 0xFFFFu);
            key2 = 0;
#pragma unroll
            for (int rr = 0; rr < 10; rr++) if (lane == rr) key2 = tt[rr];
        }
#pragma unroll
        for (int rr = 0; rr < 10; rr++) {
            u64 mx = (key > key2) ? key : key2;
            u64 wm = wave_max64(mx);
            if (key == wm)  key = 0;
            if (key2 == wm) key2 = 0;
            tt[rr] = wm;
        }
        if (it == 9) break;
        u32 thr = (u32)(tt[9] >> 32);
        u32 headhi = (u32)(crow[(it + 1) * 64] >> 32);
        if (thr > 0x80000000u && thr > headhi) break;
    }
    u64 wk = 0;
#pragma unroll
    for (int rr = 0; rr < 10; rr++) if (lane == rr) wk = tt[rr];
    sel = (lane < 10) && ((u32)(wk >> 32) > 0x80000000u);
    mid = (u32)(0xFFFF - (int)(wk & 0xFFFFu));
}

// chunk-granular ready wait (r7-validated): tid0 spins relaxed + s_sleep, then
// barrier + one acquire fence for the whole block. Called ~once per 8 batches.
__device__ __forceinline__ void wait_chunk(int c, u32 k, int tid) {
    if (tid == 0) {
        while (__hip_atomic_load(&g_chunkDone[c], __ATOMIC_RELAXED, SCOPE) < (k + 1u) * 64u)
            __builtin_amdgcn_s_sleep(2);
    }
    __syncthreads();
    __builtin_amdgcn_fence(__ATOMIC_ACQUIRE, "agent");
}

// ---------------------------------------------------------------------------
// scan role: EXACT r1-validated BATCH=8 speculative scan with r7-validated
// chunk-granular ready wait. UNCHANGED from r7/r9.
// ---------------------------------------------------------------------------
__device__ void scan_role(const u64* __restrict__ cand, float* __restrict__ out,
                          char* dsm, int tid, u32 kEpoch) {
    int* last_sel      = (int*)dsm;                       // 16 KB
    u32 (*specw)[16]   = (u32(*)[16])(dsm + 16384);       // 512 B
    u64 (*chunk0)[64]  = (u64(*)[64])(dsm + 16896);       // 4 KB
    u64* k64s          = (u64*)(dsm + 20992);             // 64 B
    u32* staleF        = (u32*)(dsm + 21056);             // 32 B
    const int lane = tid & 63;
    const int w    = tid >> 6;

    for (int j = tid; j < DOUT; j += 512) last_sel[j] = -100000;

    float tbl_r = 0.0f;                      // lane i holds tbl[i]
    {
        float p = 0.0f;
        for (int i = 0; i < 64; i++) {
            if (i == lane) tbl_r = p;
            p = fminf(p + GAMMA, 1.0f);
        }
    }
    const u64 lmask_lt = (lane == 0) ? 0ull : ((1ull << lane) - 1ull);
    __syncthreads();

    wait_chunk(0, kEpoch, tid);              // rows 0..15 live in chunk 0
    int curChunk = 0;

    u64 cpre = cand[(size_t)w * RQ + lane];
    u64 kpre = cand[(size_t)w * RQ + 64];

    for (int m0 = 0; m0 < NROWS; m0 += BATCH) {
        const int m = m0 + w;
        const u64 c  = cpre;
        const u64 kk = kpre;
        int mp = m + BATCH; if (mp >= NROWS) mp = w;
        {   // ensure the prefetch window (rows m0+8 .. m0+15) is ready
            int need = (m0 + 15 < NROWS) ? ((m0 + 15) >> 6) : (NROWS - 1) >> 6;
            if (need > curChunk) { wait_chunk(need, kEpoch, tid); curChunk = need; }
        }
        cpre = cand[(size_t)mp * RQ + lane];
        kpre = cand[(size_t)mp * RQ + 64];

        // ---- spec phase (8 waves parallel, snapshot state) ----
        bool sel; u32 mid;
        row_top10(m, c, kk, cand + (size_t)m * RQ, last_sel, tbl_r, lane,
                  lmask_lt, sel, mid);

        if (lane < 16) specw[w][lane] = 0xFFFFFFFFu;
        const u64 smask = __ballot(sel);
        const int slot = __popcll(smask & lmask_lt);
        if (sel) specw[w][slot] = mid;
        chunk0[w][lane] = c;
        if (lane == 0) k64s[w] = kk;
        __syncthreads();                                       // B1

        // ---- parallel collision check ----
        u32 my[10];
#pragma unroll
        for (int q = 0; q < 10; q++) my[q] = specw[w][q];      // broadcast reads
        bool hit = false;
#pragma unroll
        for (int pass = 0; pass < 2; pass++) {
            const int e = lane + pass * 64;
            if (e < BATCH * 10) {
                const int i = e / 10, j = e - i * 10;
                if (i < w) {
                    const u32 eid = specw[i][j];
                    if (eid != 0xFFFFFFFFu) {
#pragma unroll
                        for (int q = 0; q < 10; q++) hit |= (eid == my[q]);
                    }
                }
            }
        }
        const u32 st = __ballot(hit) ? 1u : 0u;
        if (lane == 0) staleF[w] = st;
        __syncthreads();                                       // B2

        int firstStale = BATCH;
#pragma unroll
        for (int i = BATCH - 1; i >= 0; i--) if (staleF[i]) firstStale = i;

        // ---- parallel commit of provably-valid prefix ----
        if (w < firstStale && sel) {
            out[(size_t)m * DOUT + mid] = 1.0f;
            last_sel[mid] = m;
        }
        __syncthreads();                                       // B3

        // ---- serial tail (wave 0), r10-validated fixup ----
        if (w == 0 && firstStale < BATCH) {
            for (int i = firstStale; i < BATCH; i++) {
                const int mi = m0 + i;
                const u32 sid = (lane < 10) ? specw[i][lane] : 0xFFFFFFFFu;
                const bool has = (sid != 0xFFFFFFFFu);
                const int ls2 = has ? last_sel[sid] : -100000;
                const u64 stale = __ballot(has && (ls2 >= m0));
                if (stale == 0ull) {
                    if (has) {
                        out[(size_t)mi * DOUT + sid] = 1.0f;
                        last_sel[sid] = mi;
                    }
                } else {
                    bool s2; u32 mid2;
                    row_top10(mi, chunk0[i][lane], k64s[i],
                              cand + (size_t)mi * RQ, last_sel, tbl_r, lane,
                              lmask_lt, s2, mid2);
                    if (s2) {
                        out[(size_t)mi * DOUT + mid2] = 1.0f;
                        last_sel[mid2] = mi;
                    }
                }
            }
        }
        __syncthreads();                                       // B4
    }
}

// ---------------------------------------------------------------------------
// merged topk+scan (EXACT r7/r9 config): 256 blocks x 512 threads, 1 block/CU.
// Block 0 = scan; blocks 1..255 = topk workers on an atomic ticket queue.
// ---------------------------------------------------------------------------
__global__ __launch_bounds__(512, 2)
void topk_scan_kernel(float* __restrict__ H, float* __restrict__ out) {
    extern __shared__ char dsm[];
    __shared__ u32 sh_k, sh_t;
    const int tid = threadIdx.x;

    if (tid == 0)
        sh_k = __hip_atomic_fetch_add(&g_blk, 1u, __ATOMIC_RELAXED, SCOPE) >> 8;
    __syncthreads();
    const u32 k = sh_k;

    if (blockIdx.x == 0) {            // ---- scan block ----
        scan_role((const u64*)H, out, dsm, tid, k);
        return;
    }
    // ---- worker: topk tickets (ascending) ----
    for (;;) {
        __syncthreads();
        if (tid == 0)
            sh_t = __hip_atomic_fetch_add(&g_tq, 1u, __ATOMIC_RELAXED, SCOPE) - k * TQ_SPAN;
        __syncthreads();
        u32 r = sh_t;
        if (r >= 8192u) break;
        topk_row(r, H, out, dsm, tid, k);
    }
}

// ---------------------------------------------------------------------------
// r11 ABLATION PROBE (runs LAST, solo, 2 passes): exact scan body but the
// serial tail does DIRECT COMMIT with no stale-ballot/no recompute.
// Commits go to last_sel (LDS, keeps dynamics live) + H free space (floats
// 1280..3327 of each 4096-float row; cand occupies 0..1279; `out` untouched).
// Measures the tail's ballot+recompute marginal: marg = 1850us - dur/2.
// Output is intentionally meaningless scratch.
// ---------------------------------------------------------------------------
__global__ __launch_bounds__(512)
void scan_probe(const u64* __restrict__ cand, float* __restrict__ Hf) {
    __shared__ int last_sel[DOUT];
    __shared__ u32 specw[BATCH][16];
    __shared__ u64 chnk[BATCH][64];
    __shared__ u64 k64s[BATCH];
    __shared__ u32 staleF[BATCH];
    const int tid  = threadIdx.x;
    const int lane = tid & 63;
    const int w    = tid >> 6;

    float tbl_r = 0.0f;
    {
        float p = 0.0f;
        for (int i = 0; i < 64; i++) {
            if (i == lane) tbl_r = p;
            p = fminf(p + GAMMA, 1.0f);
        }
    }
    const u64 lmask_lt = (lane == 0) ? 0ull : ((1ull << lane) - 1ull);

    for (int pass = 0; pass < 2; ++pass) {
        for (int j = tid; j < DOUT; j += 512) last_sel[j] = -100000;
        __syncthreads();

        u64 cpre = cand[(size_t)w * RQ + lane];
        u64 kpre = cand[(size_t)w * RQ + 64];

        for (int m0 = 0; m0 < NROWS; m0 += BATCH) {
            const int m = m0 + w;
            const u64 c  = cpre;
            const u64 kk = kpre;
            int mp = m + BATCH; if (mp >= NROWS) mp = w;
            cpre = cand[(size_t)mp * RQ + lane];
            kpre = cand[(size_t)mp * RQ + 64];

            bool sel; u32 mid;
            row_top10(m, c, kk, cand + (size_t)m * RQ, last_sel, tbl_r, lane,
                      lmask_lt, sel, mid);

            if (lane < 16) specw[w][lane] = 0xFFFFFFFFu;
            const u64 smask = __ballot(sel);
            const int slot = __popcll(smask & lmask_lt);
            if (sel) specw[w][slot] = mid;
            chnk[w][lane] = c;
            if (lane == 0) k64s[w] = kk;
            __syncthreads();                                   // B1

            u32 my[10];
#pragma unroll
            for (int q = 0; q < 10; q++) my[q] = specw[w][q];
            bool hit = false;
#pragma unroll
            for (int pass2 = 0; pass2 < 2; pass2++) {
                const int e = lane + pass2 * 64;
                if (e < BATCH * 10) {
                    const int i = e / 10, j = e - i * 10;
                    if (i < w) {
                        const u32 eid = specw[i][j];
                        if (eid != 0xFFFFFFFFu) {
#pragma unroll
                            for (int q = 0; q < 10; q++) hit |= (eid == my[q]);
                        }
                    }
                }
            }
            const u32 st = __ballot(hit) ? 1u : 0u;
            if (lane == 0) staleF[w] = st;
            __syncthreads();                                   // B2

            int firstStale = BATCH;
#pragma unroll
            for (int i = BATCH - 1; i >= 0; i--) if (staleF[i]) firstStale = i;

            if (w < firstStale && sel) {
                Hf[(size_t)m * DOUT + 1280 + (mid & 2047)] = 1.0f;
                last_sel[mid] = m;
            }
            __syncthreads();                                   // B3

            // ---- tail WITHOUT stale-ballot / recompute: direct commit ----
            if (w == 0 && firstStale < BATCH) {
                for (int i = firstStale; i < BATCH; i++) {
                    const int mi = m0 + i;
                    const u32 sid = (lane < 10) ? specw[i][lane] : 0xFFFFFFFFu;
                    if (sid != 0xFFFFFFFFu) {
                        Hf[(size_t)mi * DOUT + 1280 + (sid & 2047)] = 1.0f;
                        last_sel[sid] = mi;
                    }
                }
            }
            __syncthreads();                                   // B4
        }
    }
}

// ---------------------------------------------------------------------------
extern "C" void kernel_launch(void* const* d_in, const int* in_sizes, int n_in,
                              void* d_out, int out_size, void* d_ws, size_t ws_size,
                              hipStream_t stream) {
    const float* X  = (const float*)d_in[0];   // 8192 x 1024 f32
    const float* Wt = (const float*)d_in[1];   // 4096 x 1024 f32
    const float* b  = (const float*)d_in[2];   // 4096 f32
    // d_in[3] = k == 10 (beacon-verified)
    float* out = (float*)d_out;
    float* H   = (float*)d_ws;                 // 128 MB (beacon-verified)
    (void)in_sizes; (void)n_in; (void)out_size; (void)ws_size;

    // f16-split scratch lives in d_out (48 MB), consumed by the GEMM and then
    // fully overwritten by topk's per-row zeroing + scan's commits.
    char* ob = (char*)d_out;
    _Float16* X1 = (_Float16*)(ob);                                  // 16 MB
    _Float16* X2 = (_Float16*)(ob + (size_t)16 * 1024 * 1024);       // 16 MB
    _Float16* W1 = (_Float16*)(ob + (size_t)32 * 1024 * 1024);       //  8 MB
    _Float16* W2 = (_Float16*)(ob + (size_t)40 * 1024 * 1024);       //  8 MB

    split_kernel<<<dim3(6144), 256, 0, stream>>>(X, Wt, X1, X2, W1, W2);
    gemm_f16x2_mfma<<<dim3(DOUT / 128, NROWS / 128), 512, 0, stream>>>(X1, X2, W1, W2, b, H);
    topk_scan_kernel<<<dim3(256), dim3(512), 43008, stream>>>(H, out);
    // ablation probe (2-pass, solo): reads cand from H, scribbles H free space
    scan_probe<<<dim3(1), dim3(512), 0, stream>>>((const u64*)H, H);
}

// Round 14
// 2494.722 us; speedup vs baseline: 2.2051x; 2.2051x over previous
//
#include <hip/hip_runtime.h>
#include <cstdint>
#include <cstddef>

typedef unsigned long long u64;
typedef unsigned int u32;

#define NROWS 8192
#define DIN   1024
#define DOUT  4096
#define GAMMA 0.01618f
#define NC    640                 // exact candidate depth: 620 max suppressed + 10 + margin
#define RQ    2048                // u64 stride between candidate rows (16 KB = one H row)
#define BATCH 8                   // speculative rows per batch (r1-validated structure)
#define NCHUNK 128                // 8192 / 64 rows per ready-chunk
#define TQ_SPAN 8447u             // 8192 topk tickets + 255 overshoots per launch

typedef _Float16 f16x8 __attribute__((ext_vector_type(8)));
typedef float    f32x4 __attribute__((ext_vector_type(4)));

// ---- persistent device state: MONOTONIC across launches (no reset needed) ----
__device__ u32 g_blk = 0;                 // +256 per launch; epoch k = val>>8
__device__ u32 g_tq  = 0;                 // topk ticket counter: +TQ_SPAN per launch
__device__ u32 g_chunkDone[NCHUNK] = {};  // per-64-row chunk: +64 per launch

#define SCOPE __HIP_MEMORY_SCOPE_AGENT

// monotone order-preserving fp32 -> u32 (ascending); s>0 <=> key > 0x80000000
__device__ __forceinline__ u32 mono_key(float f) {
    u32 u = __float_as_uint(f);
    return (u & 0x80000000u) ? ~u : (u | 0x80000000u);
}
__device__ __forceinline__ u32 unmono_key(u32 u) {
    return (u & 0x80000000u) ? (u ^ 0x80000000u) : ~u;
}

__device__ __forceinline__ u64 wave_max64(u64 x) {
#pragma unroll
    for (int off = 32; off >= 1; off >>= 1) {
        u32 lo = (u32)x, hi = (u32)(x >> 32);
        u32 olo = __shfl_xor(lo, off, 64);
        u32 ohi = __shfl_xor(hi, off, 64);
        u64 o = ((u64)ohi << 32) | olo;
        if (o > x) x = o;
    }
    return x;
}
__device__ __forceinline__ u64 shfl_u64(u64 x, int src) {
    u32 lo = __shfl((u32)x, src, 64);
    u32 hi = __shfl((u32)(x >> 32), src, 64);
    return ((u64)hi << 32) | lo;
}

__device__ __forceinline__ void gl16(const void* g, void* l) {
    __builtin_amdgcn_global_load_lds(
        (const __attribute__((address_space(1))) unsigned int*)g,
        (__attribute__((address_space(3))) unsigned int*)l, 16, 0, 0);
}

// ---------------------------------------------------------------------------
// K0 (exact r1, validated): split f32 -> f16 hi/lo pair, K-PERMUTED layout.
// ---------------------------------------------------------------------------
__global__ __launch_bounds__(256)
void split_kernel(const float* __restrict__ X, const float* __restrict__ W,
                  _Float16* __restrict__ X1, _Float16* __restrict__ X2,
                  _Float16* __restrict__ W1, _Float16* __restrict__ W2) {
    int t = blockIdx.x * 256 + threadIdx.x;
    const int NXG = (NROWS * DIN) / 8;       // 1048576 granules of 8
    const int NWG = (DOUT * DIN) / 8;        // 524288
    if (t >= NXG + NWG) return;
    const float* src; _Float16* d1; _Float16* d2; int row, g8;
    if (t < NXG) { src = X; d1 = X1; d2 = X2; row = t >> 7; g8 = t & 127; }
    else { int u = t - NXG; src = W; d1 = W1; d2 = W2; row = u >> 7; g8 = u & 127; }
    const int kb = g8 >> 2, gp = g8 & 3;
    const int g  = gp ^ ((row >> 1) & 3);
    const int kbase = kb * 32 + g * 4;
    const float* p = src + (size_t)row * DIN + kbase;
    float4 lo = *(const float4*)p;           // k = kbase .. kbase+3   (e=0..3)
    float4 hi = *(const float4*)(p + 16);    // k = kbase+16 .. +19    (e=4..7)
    float xs[8] = {lo.x, lo.y, lo.z, lo.w, hi.x, hi.y, hi.z, hi.w};
    f16x8 v1, v2;
#pragma unroll
    for (int e = 0; e < 8; ++e) {
        float x  = xs[e];
        float x1 = (float)(_Float16)x;
        if (fabsf(x1) < 6.103515625e-05f) x1 = 0.0f;   // f16 min normal
        v1[e] = (_Float16)x1;
        v2[e] = (_Float16)((x - x1) * 2048.0f);
    }
    size_t o = (size_t)row * DIN + (size_t)g8 * 8;
    *(f16x8*)(d1 + o) = v1;
    *(f16x8*)(d2 + o) = v2;
}

// ---------------------------------------------------------------------------
// K1 v4 (r11-validated, absmax 0.0): 128x128 tile, 8 waves (2M x 4N), 2-phase
// double-buffered global_load_lds staging (64 KB LDS, 2 blocks/CU). BIT-EXACT
// vs r9 per output element (same k-order, 3-MFMA sequence, f64 cadence).
// ---------------------------------------------------------------------------
__global__ __launch_bounds__(512, 2)
void gemm_f16x2_mfma(const _Float16* __restrict__ X1, const _Float16* __restrict__ X2,
                     const _Float16* __restrict__ W1, const _Float16* __restrict__ W2,
                     const float* __restrict__ bias, float* __restrict__ H) {
    __shared__ _Float16 SM[2][16384];   // 64 KB: per buf A1@0 A2@4096 B1@8192 B2@12288
    const int tid  = threadIdx.x;
    const int lane = tid & 63, w = tid >> 6;
    const int wm = w >> 2, wn = w & 3;
    const int m0 = blockIdx.y * 128, n0 = blockIdx.x * 128;

    // --- staging plan: 2048 granules x 16B per K-step, 4 per thread ---
    const char* gp4[4];
    unsigned loff[4];
#pragma unroll
    for (int q = 0; q < 4; ++q) {
        int G = tid + q * 512;
        const char* base; int rowg, c;
        if (G < 1024) {                       // A region: 2 splits x 128 rows x 4
            int s = G >> 9, rem = G & 511; rowg = m0 + (rem >> 2); c = rem & 3;
            base = (const char*)(s ? X2 : X1);
        } else {                              // B region: 2 splits x 128 rows x 4
            int Gb = G - 1024;
            int s = Gb >> 9, rem = Gb & 511; rowg = n0 + (rem >> 2); c = rem & 3;
            base = (const char*)(s ? W2 : W1);
        }
        gp4[q]  = base + (size_t)rowg * (DIN * 2) + (size_t)c * 16;
        loff[q] = (unsigned)((w * 64 + q * 512) * 16);   // wave-uniform LDS base
    }

    f32x4 accHH[4][2], accM[4][2];
    double hd[4][2][4];
    const f32x4 z4 = {0.f, 0.f, 0.f, 0.f};
#pragma unroll
    for (int i = 0; i < 4; ++i)
#pragma unroll
        for (int j = 0; j < 2; ++j) {
            accHH[i][j] = z4; accM[i][j] = z4;
#pragma unroll
            for (int r = 0; r < 4; ++r) hd[i][j][r] = 0.0;
        }

    const int fr  = lane & 15;
    const int gsw = (lane >> 4) ^ ((lane >> 1) & 3);   // swizzled k-group slot
    const int aoff = fr * 32 + gsw * 8;
    const int boff = 8192 + (wn * 32 + fr) * 32 + gsw * 8;

    // prologue: stage K-step 0 into buf 0
#pragma unroll
    for (int q = 0; q < 4; ++q)
        gl16(gp4[q], (char*)SM[0] + loff[q]);
    __syncthreads();                          // buf0 ready

    for (int ks = 0; ks < 32; ++ks) {
        const int cur = ks & 1;
        // issue next tile's stage FIRST (overlaps with ds_read+MFMA below)
        if (ks < 31) {
#pragma unroll
            for (int q = 0; q < 4; ++q)
                gl16(gp4[q] + (size_t)(ks + 1) * 64, (char*)SM[cur ^ 1] + loff[q]);
        }

        const _Float16* SMf = SM[cur];
        f16x8 a1[4], a2[4], b1[2], b2[2];
#pragma unroll
        for (int i = 0; i < 4; ++i) {
            const _Float16* pa = SMf + (wm * 64 + i * 16) * 32 + aoff;
            a1[i] = *(const f16x8*)pa;
            a2[i] = *(const f16x8*)(pa + 4096);          // split-1, +8 KB
        }
#pragma unroll
        for (int j = 0; j < 2; ++j) {
            const _Float16* pb = SMf + boff + j * 16 * 32;
            b1[j] = *(const f16x8*)pb;
            b2[j] = *(const f16x8*)(pb + 4096);          // split-1, +8 KB
        }
#pragma unroll
        for (int i = 0; i < 4; ++i)
#pragma unroll
            for (int j = 0; j < 2; ++j) {
                accHH[i][j] = __builtin_amdgcn_mfma_f32_16x16x32_f16(a1[i], b1[j], accHH[i][j], 0, 0, 0);
                accM[i][j]  = __builtin_amdgcn_mfma_f32_16x16x32_f16(a1[i], b2[j], accM[i][j],  0, 0, 0);
                accM[i][j]  = __builtin_amdgcn_mfma_f32_16x16x32_f16(a2[i], b1[j], accM[i][j],  0, 0, 0);
            }
        if (ks & 1) {                         // flush dominant term to f64
#pragma unroll
            for (int i = 0; i < 4; ++i)
#pragma unroll
                for (int j = 0; j < 2; ++j) {
#pragma unroll
                    for (int r = 0; r < 4; ++r) hd[i][j][r] += (double)accHH[i][j][r];
                    accHH[i][j] = z4;
                }
        }
        __syncthreads();                      // one barrier per K-step
    }

    const int fq = lane >> 4;
#pragma unroll
    for (int i = 0; i < 4; ++i)
#pragma unroll
        for (int j = 0; j < 2; ++j) {
            const int col = n0 + wn * 32 + j * 16 + fr;
            const double bb = (double)bias[col];
#pragma unroll
            for (int r = 0; r < 4; ++r) {
                const int row = m0 + wm * 64 + i * 16 + fq * 4 + r;
                double v = hd[i][j][r] + (double)accM[i][j][r] * (1.0 / 2048.0) + bb;
                float h = (float)v;
                h = (h >= 0.0f) ? h : 0.01f * h;
                H[(size_t)row * DOUT + col] = h;
            }
        }
}

// ---------------------------------------------------------------------------
// top-640 row (worker role; r3/r4/r7/r11-validated 512-thread port of K2) +
// out-row zero + chunk release-increment. EXACT r11 version (no nontemporal).
// ---------------------------------------------------------------------------
__device__ void topk_row(u32 r, float* __restrict__ H, float* __restrict__ out,
                         char* dsm, int tid, u32 k) {
    u32* skey  = (u32*)dsm;                   // 16 KB
    int* hist  = (int*)(dsm + 16384);         // 16 KB
    u64* scand = (u64*)(dsm + 32768);         // 8 KB
    int* seg   = (int*)(dsm + 40960);         // 1 KB
    int* s_b   = (int*)(dsm + 41984);
    int* s_cnt = s_b + 1;

    float* hrow = H + (size_t)r * DOUT;
#pragma unroll
    for (int c = 0; c < 2; c++) {
        int j = c * 2048 + tid * 4;
        float4 v = *(const float4*)(hrow + j);
        skey[j + 0] = mono_key(v.x); skey[j + 1] = mono_key(v.y);
        skey[j + 2] = mono_key(v.z); skey[j + 3] = mono_key(v.w);
    }
#pragma unroll
    for (int c = 0; c < 8; c++) hist[c * 512 + tid] = 0;
    if (tid == 0) *s_cnt = 0;
    __syncthreads();
#pragma unroll
    for (int c = 0; c < 2; c++) {
        int j = c * 2048 + tid * 4;
        atomicAdd(&hist[skey[j + 0] >> 20], 1);
        atomicAdd(&hist[skey[j + 1] >> 20], 1);
        atomicAdd(&hist[skey[j + 2] >> 20], 1);
        atomicAdd(&hist[skey[j + 3] >> 20], 1);
    }
    __syncthreads();
    if (tid < 256) {
        int ssum = 0;
#pragma unroll
        for (int i = 0; i < 16; i++) ssum += hist[tid * 16 + i];
        seg[tid] = ssum;
    }
    __syncthreads();
    if (tid == 0) {
        int cum = 0, ts;
        for (ts = 255; ts >= 0; ts--) {
            if (cum + seg[ts] >= NC) break;
            cum += seg[ts];
        }
        int b = 0;
        if (ts >= 0) {
            int bin;
            for (bin = ts * 16 + 15; bin >= ts * 16; bin--) {
                cum += hist[bin];
                if (cum >= NC) break;
            }
            b = (bin < ts * 16) ? ts * 16 : bin;
        }
        *s_b = b;
    }
    __syncthreads();
    const int b = *s_b;
#pragma unroll
    for (int c = 0; c < 2; c++) {
        int jb = c * 2048 + tid * 4;
#pragma unroll
        for (int q = 0; q < 4; q++) {
            int j = jb + q;
            u32 kk = skey[j];
            if ((int)(kk >> 20) >= b) {
                int pos = atomicAdd(s_cnt, 1);
                if (pos < 1024)
                    scand[pos] = ((u64)kk << 32) | (u32)(0xFFFFu - (u32)j);
            }
        }
    }
    __syncthreads();
    int C = *s_cnt; if (C > 1024) C = 1024;
    for (int j = C + tid; j < 1024; j += 512) scand[j] = 0;   // pad sorts last
    for (int size = 2; size <= 1024; size <<= 1)
        for (int stride = size >> 1; stride > 0; stride >>= 1) {
            __syncthreads();
            {
                int i = tid;
                int pos = 2 * i - (i & (stride - 1));
                u64 a = scand[pos], bb = scand[pos + stride];
                bool up = (pos & size) == 0;
                if ((a < bb) == up) { scand[pos] = bb; scand[pos + stride] = a; }
            }
        }
    __syncthreads();
    u64* cand = (u64*)hrow;
    for (int j = tid; j < NC; j += 512) cand[j] = scand[j];
    // zero this row of out (replaces host memset; must precede chunk flag)
    {
        float4 z = {0.f, 0.f, 0.f, 0.f};
        float4* po = (float4*)(out + (size_t)r * DOUT);
        po[tid] = z; po[tid + 512] = z;
    }
    __syncthreads();
    if (tid == 0)
        __hip_atomic_fetch_add(&g_chunkDone[r >> 6], 1u, __ATOMIC_RELEASE, SCOPE);
}

// ---------------------------------------------------------------------------
// r8/r9-validated per-row exact top-10 (fast path + beater-merge + fallback).
// UNCHANGED (r9 version).
// ---------------------------------------------------------------------------
__device__ __forceinline__ void row_top10(
    int m, u64 c, u64 k64, const u64* __restrict__ crow,
    const int* last_sel, float tbl_r, int lane, u64 lmask_lt,
    bool& sel, u32& mid)
{
    const int id = 0xFFFF - (int)(c & 0xFFFFu);
    int t = m - last_sel[id] - 1; if (t > 63) t = 63;
    const bool unsup = (t >= 62);            // tbl saturates to exactly 1 at 62
    const u64 mu = __ballot(unsup);
    const float phi = __shfl(tbl_r, t);
    const float v = __uint_as_float(unmono_key((u32)(c >> 32)));
    const float s = v * phi;
    const u64 skey = ((u64)mono_key(s) << 32) | (c & 0xFFFFu);
    const int nu = __popcll(mu);
    const int prefix = __popcll(mu & lmask_lt);

    bool resolved = false, win = false;
    if (nu >= 10) {
        u64 um = mu;
#pragma unroll
        for (int q = 0; q < 9; q++) um &= um - 1;
        const int lane10 = __ffsll((long long)um) - 1;
        const u64 key10 = shfl_u64(skey, lane10);
        const u64 beat = __ballot(skey > key10) & ~mu;
        u64 theta;
        if (beat == 0ull) {
            win = unsup && (prefix < 10);
            theta = key10;
        } else {
            int myExtra = 0, myrank = 64;
            u64 bm = beat;
            while (bm) {
                const int l = __ffsll((long long)bm) - 1;
                bm &= bm - 1;
                const u64 kb = shfl_u64(skey, l);
                const u64 g = __ballot(skey > kb);
                if (lane == l) myrank = __popcll(g);
                myExtra += (kb > skey) ? 1 : 0;
            }
            const bool isbeat = (beat >> lane) & 1ull;
            const int rank = unsup ? (prefix + myExtra) : (isbeat ? myrank : 64);
            win = rank < 10;
            const u64 r9 = __ballot(rank == 9);
            const int l9 = __ffsll((long long)r9) - 1;
            theta = shfl_u64(skey, l9);
        }
        resolved = ((u32)(theta >> 32) > 0x80000000u) && (theta > k64);
    }

    if (resolved) {
        sel = win; mid = (u32)id;
        return;
    }
    // ---- r6-validated exact fallback over up to 640 candidates ----
    u64 tt[10];
    u64 key = skey, key2 = 0;
#pragma unroll 1
    for (int it = 0; it < 10; it++) {
        if (it > 0) {
            u64 ck = crow[it * 64 + lane];
            u32 hbits = unmono_key((u32)(ck >> 32));
            int id2 = 0xFFFF - (int)(ck & 0xFFFFu);
            int t2 = m - last_sel[id2] - 1; if (t2 > 63) t2 = 63;
            float s2 = __uint_as_float(hbits) * __shfl(tbl_r, t2);
            key = ((u64)mono_key(s2) << 32) | (ck & 0xFFFFu);
            key2 = 0;
#pragma unroll
            for (int rr = 0; rr < 10; rr++) if (lane == rr) key2 = tt[rr];
        }
#pragma unroll
        for (int rr = 0; rr < 10; rr++) {
            u64 mx = (key > key2) ? key : key2;
            u64 wm = wave_max64(mx);
            if (key == wm)  key = 0;
            if (key2 == wm) key2 = 0;
            tt[rr] = wm;
        }
        if (it == 9) break;
        u32 thr = (u32)(tt[9] >> 32);
        u32 headhi = (u32)(crow[(it + 1) * 64] >> 32);
        if (thr > 0x80000000u && thr > headhi) break;
    }
    u64 wk = 0;
#pragma unroll
    for (int rr = 0; rr < 10; rr++) if (lane == rr) wk = tt[rr];
    sel = (lane < 10) && ((u32)(wk >> 32) > 0x80000000u);
    mid = (u32)(0xFFFF - (int)(wk & 0xFFFFu));
}

// chunk-granular ready wait (r7-validated): tid0 spins relaxed + s_sleep, then
// barrier + one acquire fence for the whole block. Called ~once per 8 batches.
__device__ __forceinline__ void wait_chunk(int c, u32 k, int tid) {
    if (tid == 0) {
        while (__hip_atomic_load(&g_chunkDone[c], __ATOMIC_RELAXED, SCOPE) < (k + 1u) * 64u)
            __builtin_amdgcn_s_sleep(2);
    }
    __syncthreads();
    __builtin_amdgcn_fence(__ATOMIC_ACQUIRE, "agent");
}

// ---------------------------------------------------------------------------
// scan role: EXACT r1-validated BATCH=8 speculative scan with r7-validated
// chunk-granular ready wait. UNCHANGED from r7/r9/r11 (unconditional B4).
// ---------------------------------------------------------------------------
__device__ void scan_role(const u64* __restrict__ cand, float* __restrict__ out,
                          char* dsm, int tid, u32 kEpoch) {
    int* last_sel      = (int*)dsm;                       // 16 KB
    u32 (*specw)[16]   = (u32(*)[16])(dsm + 16384);       // 512 B
    u64 (*chunk0)[64]  = (u64(*)[64])(dsm + 16896);       // 4 KB
    u64* k64s          = (u64*)(dsm + 20992);             // 64 B
    u32* staleF        = (u32*)(dsm + 21056);             // 32 B
    const int lane = tid & 63;
    const int w    = tid >> 6;

    for (int j = tid; j < DOUT; j += 512) last_sel[j] = -100000;

    float tbl_r = 0.0f;                      // lane i holds tbl[i]
    {
        float p = 0.0f;
        for (int i = 0; i < 64; i++) {
            if (i == lane) tbl_r = p;
            p = fminf(p + GAMMA, 1.0f);
        }
    }
    const u64 lmask_lt = (lane == 0) ? 0ull : ((1ull << lane) - 1ull);
    __syncthreads();

    wait_chunk(0, kEpoch, tid);              // rows 0..15 live in chunk 0
    int curChunk = 0;

    u64 cpre = cand[(size_t)w * RQ + lane];
    u64 kpre = cand[(size_t)w * RQ + 64];

    for (int m0 = 0; m0 < NROWS; m0 += BATCH) {
        const int m = m0 + w;
        const u64 c  = cpre;
        const u64 kk = kpre;
        int mp = m + BATCH; if (mp >= NROWS) mp = w;
        {   // ensure the prefetch window (rows m0+8 .. m0+15) is ready
            int need = (m0 + 15 < NROWS) ? ((m0 + 15) >> 6) : (NROWS - 1) >> 6;
            if (need > curChunk) { wait_chunk(need, kEpoch, tid); curChunk = need; }
        }
        cpre = cand[(size_t)mp * RQ + lane];
        kpre = cand[(size_t)mp * RQ + 64];

        // ---- spec phase (8 waves parallel, snapshot state) ----
        bool sel; u32 mid;
        row_top10(m, c, kk, cand + (size_t)m * RQ, last_sel, tbl_r, lane,
                  lmask_lt, sel, mid);

        if (lane < 16) specw[w][lane] = 0xFFFFFFFFu;
        const u64 smask = __ballot(sel);
        const int slot = __popcll(smask & lmask_lt);
        if (sel) specw[w][slot] = mid;
        chunk0[w][lane] = c;
        if (lane == 0) k64s[w] = kk;
        __syncthreads();                                       // B1

        // ---- parallel collision check ----
        u32 my[10];
#pragma unroll
        for (int q = 0; q < 10; q++) my[q] = specw[w][q];      // broadcast reads
        bool hit = false;
#pragma unroll
        for (int pass = 0; pass < 2; pass++) {
            const int e = lane + pass * 64;
            if (e < BATCH * 10) {
                const int i = e / 10, j = e - i * 10;
                if (i < w) {
                    const u32 eid = specw[i][j];
                    if (eid != 0xFFFFFFFFu) {
#pragma unroll
                        for (int q = 0; q < 10; q++) hit |= (eid == my[q]);
                    }
                }
            }
        }
        const u32 st = __ballot(hit) ? 1u : 0u;
        if (lane == 0) staleF[w] = st;
        __syncthreads();                                       // B2

        int firstStale = BATCH;
#pragma unroll
        for (int i = BATCH - 1; i >= 0; i--) if (staleF[i]) firstStale = i;

        // ---- parallel commit of provably-valid prefix ----
        if (w < firstStale && sel) {
            out[(size_t)m * DOUT + mid] = 1.0f;
            last_sel[mid] = m;
        }
        __syncthreads();                                       // B3

        // ---- serial tail (wave 0), r10-validated fixup ----
        if (w == 0 && firstStale < BATCH) {
            for (int i = firstStale; i < BATCH; i++) {
                const int mi = m0 + i;
                const u32 sid = (lane < 10) ? specw[i][lane] : 0xFFFFFFFFu;
                const bool has = (sid != 0xFFFFFFFFu);
                const int ls2 = has ? last_sel[sid] : -100000;
                const u64 stale = __ballot(has && (ls2 >= m0));
                if (stale == 0ull) {
                    if (has) {
                        out[(size_t)mi * DOUT + sid] = 1.0f;
                        last_sel[sid] = mi;
                    }
                } else {
                    bool s2; u32 mid2;
                    row_top10(mi, chunk0[i][lane], k64s[i],
                              cand + (size_t)mi * RQ, last_sel, tbl_r, lane,
                              lmask_lt, s2, mid2);
                    if (s2) {
                        out[(size_t)mi * DOUT + mid2] = 1.0f;
                        last_sel[mid2] = mi;
                    }
                }
            }
        }
        __syncthreads();                                       // B4
    }
}

// ---------------------------------------------------------------------------
// merged topk+scan (r7/r9/r11 config): 256 blocks x 512 threads, 1 block/CU.
// Block 0 = scan; blocks 1..255 = topk workers on an atomic ticket queue.
// Deadlock-impossible: workers wait on nothing; scan waits only on workers.
// ---------------------------------------------------------------------------
__global__ __launch_bounds__(512, 2)
void topk_scan_kernel(float* __restrict__ H, float* __restrict__ out) {
    extern __shared__ char dsm[];
    __shared__ u32 sh_k, sh_t;
    const int tid = threadIdx.x;

    if (tid == 0)
        sh_k = __hip_atomic_fetch_add(&g_blk, 1u, __ATOMIC_RELAXED, SCOPE) >> 8;
    __syncthreads();
    const u32 k = sh_k;

    if (blockIdx.x == 0) {            // ---- scan block ----
        scan_role((const u64*)H, out, dsm, tid, k);
        return;
    }
    // ---- worker: topk tickets (ascending) ----
    for (;;) {
        __syncthreads();
        if (tid == 0)
            sh_t = __hip_atomic_fetch_add(&g_tq, 1u, __ATOMIC_RELAXED, SCOPE) - k * TQ_SPAN;
        __syncthreads();
        u32 r = sh_t;
        if (r >= 8192u) break;
        topk_row(r, H, out, dsm, tid, k);
    }
}

// ---------------------------------------------------------------------------
extern "C" void kernel_launch(void* const* d_in, const int* in_sizes, int n_in,
                              void* d_out, int out_size, void* d_ws, size_t ws_size,
                              hipStream_t stream) {
    const float* X  = (const float*)d_in[0];   // 8192 x 1024 f32
    const float* Wt = (const float*)d_in[1];   // 4096 x 1024 f32
    const float* b  = (const float*)d_in[2];   // 4096 f32
    // d_in[3] = k == 10 (beacon-verified)
    float* out = (float*)d_out;
    float* H   = (float*)d_ws;                 // 128 MB (beacon-verified)
    (void)in_sizes; (void)n_in; (void)out_size; (void)ws_size;

    // f16-split scratch lives in d_out (48 MB), consumed by the GEMM and then
    // fully overwritten by topk's per-row zeroing + scan's commits.
    char* ob = (char*)d_out;
    _Float16* X1 = (_Float16*)(ob);                                  // 16 MB
    _Float16* X2 = (_Float16*)(ob + (size_t)16 * 1024 * 1024);       // 16 MB
    _Float16* W1 = (_Float16*)(ob + (size_t)32 * 1024 * 1024);       //  8 MB
    _Float16* W2 = (_Float16*)(ob + (size_t)40 * 1024 * 1024);       //  8 MB

    split_kernel<<<dim3(6144), 256, 0, stream>>>(X, Wt, X1, X2, W1, W2);
    gemm_f16x2_mfma<<<dim3(DOUT / 128, NROWS / 128), 512, 0, stream>>>(X1, X2, W1, W2, b, H);
    topk_scan_kernel<<<dim3(256), dim3(512), 43008, stream>>>(H, out);
}